// Round 7
// baseline (499.530 us; speedup 1.0000x reference)
//
#include <hip/hip_runtime.h>
#include <hip/hip_bf16.h>

#define T_TOK 1024
#define H_DIM 1024
#define I_DIM 1408
#define NE 16
#define NEP 18   // 16 routed + 2 pseudo (shared expert = two I=1408 halves)
#define BM 256   // token tile per block

typedef __attribute__((ext_vector_type(8))) __bf16 bf16x8;
typedef __attribute__((ext_vector_type(4))) float f32x4;

__device__ __forceinline__ bf16x8 cvt8(float4 a, float4 b) {
    bf16x8 r;
    r[0] = (__bf16)a.x; r[1] = (__bf16)a.y; r[2] = (__bf16)a.z; r[3] = (__bf16)a.w;
    r[4] = (__bf16)b.x; r[5] = (__bf16)b.y; r[6] = (__bf16)b.z; r[7] = (__bf16)b.w;
    return r;
}

// async global->LDS DMA, 16B per lane; LDS dest = wave-uniform base + lane*16
__device__ __forceinline__ void gll16(const float* g, float* l) {
    __builtin_amdgcn_global_load_lds(
        (const __attribute__((address_space(1))) void*)g,
        (__attribute__((address_space(3))) void*)l, 16, 0, 0);
}

// ---------------------------------------------------------------- gate ------
__global__ __launch_bounds__(64) void gate_kernel(
    const float* __restrict__ x, const float* __restrict__ gw,
    const float* __restrict__ gb,
    int* __restrict__ counts, int* __restrict__ etok, float* __restrict__ ew)
{
    const int t = blockIdx.x;
    const int lane = threadIdx.x;
    float s[NE];
#pragma unroll
    for (int e = 0; e < NE; ++e) s[e] = 0.f;
    const float* xr = x + (size_t)t * H_DIM;
    for (int i = lane; i < H_DIM; i += 64) {
        float xv = xr[i];
#pragma unroll
        for (int e = 0; e < NE; ++e) s[e] += xv * gw[e * H_DIM + i];
    }
#pragma unroll
    for (int e = 0; e < NE; ++e) {
        for (int off = 32; off > 0; off >>= 1) s[e] += __shfl_xor(s[e], off);
    }
    if (lane == 0) {
        float scores[NE], sfc[NE];
#pragma unroll
        for (int e = 0; e < NE; ++e) {
            scores[e] = 1.f / (1.f + __expf(-s[e]));
            sfc[e] = scores[e] + gb[e];
        }
        float gsc[4];
#pragma unroll
        for (int g = 0; g < 4; ++g) {
            float m1 = -1e30f, m2 = -1e30f;
#pragma unroll
            for (int j = 0; j < 4; ++j) {
                float v = sfc[4 * g + j];
                if (v > m1) { m2 = m1; m1 = v; } else if (v > m2) { m2 = v; }
            }
            gsc[g] = m1 + m2;
        }
        int g1 = 0;
        for (int g = 1; g < 4; ++g) if (gsc[g] > gsc[g1]) g1 = g;
        int g2 = -1;
        for (int g = 0; g < 4; ++g) {
            if (g == g1) continue;
            if (g2 < 0 || gsc[g] > gsc[g2]) g2 = g;
        }
        float tmp[NE];
#pragma unroll
        for (int e = 0; e < NE; ++e) {
            int gg = e >> 2;
            tmp[e] = (gg == g1 || gg == g2) ? sfc[e] : 0.0f;
        }
        int idxs[4]; float wk[4]; float wsum = 0.f;
#pragma unroll
        for (int k = 0; k < 4; ++k) {
            int bi = 0;
            for (int e = 1; e < NE; ++e) if (tmp[e] > tmp[bi]) bi = e;
            idxs[k] = bi; wk[k] = scores[bi]; wsum += scores[bi];
            tmp[bi] = -1e30f;
        }
        float inv = 1.f / (wsum + 1e-20f);
        for (int k = 0; k < 4; ++k) {
            int e = idxs[k];
            int pos = atomicAdd(&counts[e], 1);
            etok[e * T_TOK + pos] = t;
            ew[e * T_TOK + pos] = wk[k] * inv;   // SCALE = 1.0
        }
    }
}

// ---------------------------------------------------- x f32 -> bf16 ---------
__global__ __launch_bounds__(256) void cvtx_kernel(
    const float* __restrict__ x, __hip_bfloat16* __restrict__ x_bf)
{
    int i = (blockIdx.x * 256 + threadIdx.x) * 4;
    float4 v = ((const float4*)x)[i >> 2];
    x_bf[i + 0] = __float2bfloat16(v.x);
    x_bf[i + 1] = __float2bfloat16(v.y);
    x_bf[i + 2] = __float2bfloat16(v.z);
    x_bf[i + 3] = __float2bfloat16(v.w);
}

// ------------------------------------------------------------- gate/up ------
// Grid (22, ne, 4). Block = [BM=256 tok x 64 I-cols]; wave w owns 64 tokens.
// B staged as RAW F32 via global_load_lds (fire-and-forget DMA, no VGPR
// round trip, no ds_write). Ring-2 LDS, one {vmcnt(0); s_barrier} per step;
// next-buffer DMA issued right after the barrier so ~8KB/wave stays in
// flight continuously. Reads are XOR-swizzled (slot ^= row&7 within each
// 128B row) with the SAME involution pre-applied to the global source
// addresses (global_load_lds writes LDS linearly). cvt f32->bf16 at read.
__global__ __launch_bounds__(256, 2) void gateup_kernel(
    const __hip_bfloat16* __restrict__ x_bf,
    const float* __restrict__ gproj, const float* __restrict__ uproj,
    const float* __restrict__ sgw, const float* __restrict__ suw,
    const int* __restrict__ counts, const int* __restrict__ etok,
    __hip_bfloat16* __restrict__ act, int e0)
{
    const int slot = blockIdx.y;
    const int e = e0 + slot;
    const int cnt = (e < NE) ? counts[e] : T_TOK;
    const int row0 = blockIdx.z * BM;
    if (row0 >= cnt) return;

    __shared__ int toks[BM];
    __shared__ __align__(16) float Bg[2][2048];   // [buf][64 rows x 32 K]
    __shared__ __align__(16) float Bu[2][2048];

    const int tid = threadIdx.x;
    {
        int r = row0 + tid;
        toks[tid] = (e < NE) ? ((r < cnt) ? etok[e * T_TOK + r] : 0) : r;
    }

    const int nb0 = blockIdx.x * 64;
    const float *wg, *wu;
    if (e < NE) {
        wg = gproj + (size_t)e * I_DIM * H_DIM;
        wu = uproj + (size_t)e * I_DIM * H_DIM;
    } else {
        wg = sgw + (size_t)(e - NE) * I_DIM * H_DIM;
        wu = suw + (size_t)(e - NE) * I_DIM * H_DIM;
    }

    const int lane = tid & 63;
    const int w = tid >> 6;
    const int col = lane & 15, kq = lane >> 4;

    // producer: wave w stages chunks {2w,2w+1} of Bg and Bu (1KB each).
    // chunk c covers rows c*8..c*8+8; lane l -> LDS byte c*1024 + l*16,
    // i.e. row = c*8 + (l>>3), slot s = l&7. Source slot = s ^ (row&7).
    const int lr8 = lane >> 3;
    const int sgx = (lane & 7) ^ lr8;          // (row&7) == lr8 (c*8 aligned)
    const float* pgW[2]; const float* puW[2];
#pragma unroll
    for (int j = 0; j < 2; ++j) {
        int c = 2 * w + j;
        pgW[j] = wg + (size_t)(nb0 + c * 8 + lr8) * H_DIM + sgx * 4;
        puW[j] = wu + (size_t)(nb0 + c * 8 + lr8) * H_DIM + sgx * 4;
    }

    // consumer: fragment ni, half h reads row=ni*16+col, f32 idx =
    // row*32 + ((kq*2+h)^(row&7))*4  (swizzled slot)
    int offs[4][2];
#pragma unroll
    for (int ni = 0; ni < 4; ++ni) {
        int row = ni * 16 + col;
#pragma unroll
        for (int h = 0; h < 2; ++h)
            offs[ni][h] = row * 32 + (((kq * 2 + h) ^ (row & 7)) << 2);
    }

    // prologue: stage buffer 0 (k=0); toks barrier also drains the DMA
#pragma unroll
    for (int j = 0; j < 2; ++j) gll16(pgW[j], &Bg[0][(2 * w + j) * 256]);
#pragma unroll
    for (int j = 0; j < 2; ++j) gll16(puW[j], &Bu[0][(2 * w + j) * 256]);
    __syncthreads();

    const __hip_bfloat16* ar[4];
#pragma unroll
    for (int mi = 0; mi < 4; ++mi)
        ar[mi] = x_bf + (size_t)toks[w * 64 + mi * 16 + col] * H_DIM + kq * 8;

    f32x4 accg[4][4], accu[4][4];
#pragma unroll
    for (int mi = 0; mi < 4; ++mi)
#pragma unroll
        for (int ni = 0; ni < 4; ++ni) {
            accg[mi][ni] = (f32x4){0.f, 0.f, 0.f, 0.f};
            accu[mi][ni] = (f32x4){0.f, 0.f, 0.f, 0.f};
        }

    for (int k = 0; k < 32; ++k) {
        const int buf = k & 1;
        asm volatile("s_waitcnt vmcnt(0)" ::: "memory");  // buf k DMA arrived
        __builtin_amdgcn_s_barrier();                      // all waves' too
        __builtin_amdgcn_sched_barrier(0);                 // no hoist past bar
        // A fragments for this step (L2-resident x_bf); issued BEFORE the
        // DMA so the compiler's A-wait is a counted vmcnt that keeps the
        // k+1 staging in flight.
        bf16x8 a[4];
#pragma unroll
        for (int mi = 0; mi < 4; ++mi) a[mi] = *(const bf16x8*)(ar[mi] + k * 32);
        __builtin_amdgcn_sched_barrier(0);
        if (k + 1 < 32) {   // stage k+1 into the other buffer
#pragma unroll
            for (int j = 0; j < 2; ++j)
                gll16(pgW[j] + (k + 1) * 32, &Bg[buf ^ 1][(2 * w + j) * 256]);
#pragma unroll
            for (int j = 0; j < 2; ++j)
                gll16(puW[j] + (k + 1) * 32, &Bu[buf ^ 1][(2 * w + j) * 256]);
        }
        __builtin_amdgcn_sched_barrier(0);
        bf16x8 bg[4], bu[4];
#pragma unroll
        for (int ni = 0; ni < 4; ++ni) {
            float4 lo = *(const float4*)&Bg[buf][offs[ni][0]];
            float4 hi = *(const float4*)&Bg[buf][offs[ni][1]];
            bg[ni] = cvt8(lo, hi);
            float4 lo2 = *(const float4*)&Bu[buf][offs[ni][0]];
            float4 hi2 = *(const float4*)&Bu[buf][offs[ni][1]];
            bu[ni] = cvt8(lo2, hi2);
        }
#pragma unroll
        for (int mi = 0; mi < 4; ++mi)
#pragma unroll
            for (int ni = 0; ni < 4; ++ni) {
                accg[mi][ni] = __builtin_amdgcn_mfma_f32_16x16x32_bf16(a[mi], bg[ni], accg[mi][ni], 0, 0, 0);
                accu[mi][ni] = __builtin_amdgcn_mfma_f32_16x16x32_bf16(a[mi], bu[ni], accu[mi][ni], 0, 0, 0);
            }
    }

    // epilogue: silu(g)*u -> act (zeros for padded rows so down reads zeros)
#pragma unroll
    for (int mi = 0; mi < 4; ++mi)
#pragma unroll
        for (int ni = 0; ni < 4; ++ni)
#pragma unroll
            for (int r = 0; r < 4; ++r) {
                int lrow = w * 64 + mi * 16 + kq * 4 + r;
                int grow = row0 + lrow;
                float g = accg[mi][ni][r];
                float a = (grow < cnt) ? (g / (1.f + __expf(-g)) * accu[mi][ni][r]) : 0.f;
                act[((size_t)slot * T_TOK + grow) * I_DIM + nb0 + ni * 16 + col] =
                    __float2bfloat16(a);
            }
}

// ---------------------------------------------------------------- down ------
// 1-D grid, XCD-clustered (hw%8 picks the group -> all 16 nb-blocks of one
// (slot,z) share one XCD's L2 for the act slice). Same DMA ring-2 K-loop.
__global__ __launch_bounds__(256, 3) void down_kernel(
    const __hip_bfloat16* __restrict__ act,
    const float* __restrict__ dproj, const float* __restrict__ sdw,
    const int* __restrict__ counts, const int* __restrict__ etok,
    const float* __restrict__ ew, float* __restrict__ y, int e0, int ne)
{
    const int hw = blockIdx.x;
    const int c8 = hw & 7, t = hw >> 3;
    const int nbt = t & 15, gh = t >> 4;
    const int g = c8 + 8 * gh;
    if (g >= ne * 4) return;           // Gp padding
    const int slot = g % ne;
    const int z = g / ne;

    const int e = e0 + slot;
    const int cnt = (e < NE) ? counts[e] : T_TOK;
    const int row0 = z * BM;
    if (row0 >= cnt) return;

    __shared__ int toks[BM];
    __shared__ float wts[BM];
    __shared__ __align__(16) float Bd[2][2048];

    const int tid = threadIdx.x;
    {
        int r = row0 + tid;
        if (e < NE) {
            bool ok = r < cnt;
            toks[tid] = ok ? etok[e * T_TOK + r] : 0;
            wts[tid]  = ok ? ew[e * T_TOK + r] : 0.f;
        } else { toks[tid] = r; wts[tid] = 1.f; }
    }

    const int nb0 = nbt * 64;
    const float* wd;
    int wstride;
    if (e < NE) { wd = dproj + (size_t)e * H_DIM * I_DIM; wstride = I_DIM; }
    else        { wd = sdw + (size_t)(e - NE) * I_DIM;    wstride = 2 * I_DIM; }

    const int lane = tid & 63;
    const int w = tid >> 6;
    const int col = lane & 15, kq = lane >> 4;

    const int lr8 = lane >> 3;
    const int sgx = (lane & 7) ^ lr8;
    const float* pdW[2];
#pragma unroll
    for (int j = 0; j < 2; ++j) {
        int c = 2 * w + j;
        pdW[j] = wd + (size_t)(nb0 + c * 8 + lr8) * wstride + sgx * 4;
    }

    int offs[4][2];
#pragma unroll
    for (int ni = 0; ni < 4; ++ni) {
        int row = ni * 16 + col;
#pragma unroll
        for (int h = 0; h < 2; ++h)
            offs[ni][h] = row * 32 + (((kq * 2 + h) ^ (row & 7)) << 2);
    }

#pragma unroll
    for (int j = 0; j < 2; ++j) gll16(pdW[j], &Bd[0][(2 * w + j) * 256]);
    __syncthreads();   // toks/wts visible + prologue DMA drained

    const __hip_bfloat16* ar[4];
#pragma unroll
    for (int mi = 0; mi < 4; ++mi)
        ar[mi] = act + ((size_t)slot * T_TOK + row0 + w * 64 + mi * 16 + col) * I_DIM + kq * 8;

    f32x4 acc[4][4];
#pragma unroll
    for (int mi = 0; mi < 4; ++mi)
#pragma unroll
        for (int ni = 0; ni < 4; ++ni) acc[mi][ni] = (f32x4){0.f, 0.f, 0.f, 0.f};

    const int KS = I_DIM / 32;   // 44
    for (int k = 0; k < KS; ++k) {
        const int buf = k & 1;
        asm volatile("s_waitcnt vmcnt(0)" ::: "memory");
        __builtin_amdgcn_s_barrier();
        __builtin_amdgcn_sched_barrier(0);
        bf16x8 a[4];
#pragma unroll
        for (int mi = 0; mi < 4; ++mi) a[mi] = *(const bf16x8*)(ar[mi] + k * 32);
        __builtin_amdgcn_sched_barrier(0);
        if (k + 1 < KS) {
#pragma unroll
            for (int j = 0; j < 2; ++j)
                gll16(pdW[j] + (k + 1) * 32, &Bd[buf ^ 1][(2 * w + j) * 256]);
        }
        __builtin_amdgcn_sched_barrier(0);
        bf16x8 b[4];
#pragma unroll
        for (int ni = 0; ni < 4; ++ni) {
            float4 lo = *(const float4*)&Bd[buf][offs[ni][0]];
            float4 hi = *(const float4*)&Bd[buf][offs[ni][1]];
            b[ni] = cvt8(lo, hi);
        }
#pragma unroll
        for (int mi = 0; mi < 4; ++mi)
#pragma unroll
            for (int ni = 0; ni < 4; ++ni)
                acc[mi][ni] = __builtin_amdgcn_mfma_f32_16x16x32_bf16(a[mi], b[ni], acc[mi][ni], 0, 0, 0);
    }

#pragma unroll
    for (int mi = 0; mi < 4; ++mi)
#pragma unroll
        for (int ni = 0; ni < 4; ++ni)
#pragma unroll
            for (int r = 0; r < 4; ++r) {
                int lrow = w * 64 + mi * 16 + kq * 4 + r;
                int grow = row0 + lrow;
                if (grow < cnt)
                    atomicAdd(&y[(size_t)toks[lrow] * H_DIM + nb0 + ni * 16 + col],
                              acc[mi][ni][r] * wts[lrow]);
            }
}

// -------------------------------------------------------------- launch ------
extern "C" void kernel_launch(void* const* d_in, const int* in_sizes, int n_in,
                              void* d_out, int out_size, void* d_ws, size_t ws_size,
                              hipStream_t stream) {
    (void)in_sizes; (void)n_in; (void)out_size;
    const float* x  = (const float*)d_in[0];
    const float* gw = (const float*)d_in[1];
    const float* gb = (const float*)d_in[2];
    const float* gp = (const float*)d_in[3];
    const float* up = (const float*)d_in[4];
    const float* dp = (const float*)d_in[5];
    const float* sg = (const float*)d_in[6];
    const float* su = (const float*)d_in[7];
    const float* sd = (const float*)d_in[8];
    float* out = (float*)d_out;

    char* ws = (char*)d_ws;
    int*   counts = (int*)ws;                                    // @0      (64 B)
    int*   etok   = (int*)(ws + 256);                            // 64 KB
    float* ew     = (float*)(ws + 256 + 65536);                  // 64 KB
    __hip_bfloat16* x_bf = (__hip_bfloat16*)(ws + 131328);       // 2 MB
    __hip_bfloat16* act  = (__hip_bfloat16*)(ws + 2228480);      // up to ~52 MB

    size_t fixed = 2228480;
    size_t per_e = (size_t)T_TOK * I_DIM * 2;                    // 2.75 MB / slot
    int cap = NEP;
    if (ws_size < fixed + (size_t)NEP * per_e) {
        cap = (ws_size > fixed + per_e) ? (int)((ws_size - fixed) / per_e) : 1;
        if (cap < 1) cap = 1;
    }

    hipMemsetAsync(ws, 0, 256, stream);                          // counts
    hipMemsetAsync(out, 0, (size_t)T_TOK * H_DIM * 4, stream);   // d_out is poisoned

    gate_kernel<<<dim3(T_TOK), dim3(64), 0, stream>>>(x, gw, gb, counts, etok, ew);
    cvtx_kernel<<<dim3(1024), dim3(256), 0, stream>>>(x, x_bf);

    for (int e0 = 0; e0 < NEP; e0 += cap) {
        int ne = NEP - e0 < cap ? NEP - e0 : cap;
        gateup_kernel<<<dim3(I_DIM / 64, ne, T_TOK / BM), dim3(256), 0, stream>>>(
            x_bf, gp, up, sg, su, counts, etok, act, e0);
        int Gp = ((ne * 4 + 7) / 8) * 8;                         // XCD-bijective pad
        down_kernel<<<dim3(16 * Gp), dim3(256), 0, stream>>>(
            act, dp, sd, counts, etok, ew, out, e0, ne);
    }
}

// Round 12
// 488.777 us; speedup vs baseline: 1.0220x; 1.0220x over previous
//
#include <hip/hip_runtime.h>
#include <hip/hip_bf16.h>

#define T_TOK 1024
#define H_DIM 1024
#define I_DIM 1408
#define NE 16
#define NEP 18   // 16 routed + 2 pseudo (shared expert = two I=1408 halves)
#define BM 256   // token tile per block

typedef __attribute__((ext_vector_type(8))) __bf16 bf16x8;
typedef __attribute__((ext_vector_type(4))) float f32x4;

__device__ __forceinline__ bf16x8 cvt8(float4 a, float4 b) {
    bf16x8 r;
    r[0] = (__bf16)a.x; r[1] = (__bf16)a.y; r[2] = (__bf16)a.z; r[3] = (__bf16)a.w;
    r[4] = (__bf16)b.x; r[5] = (__bf16)b.y; r[6] = (__bf16)b.z; r[7] = (__bf16)b.w;
    return r;
}

// async global->LDS DMA, 16B per lane; LDS dest = wave-uniform base + lane*16
__device__ __forceinline__ void gll16(const float* g, float* l) {
    __builtin_amdgcn_global_load_lds(
        (const __attribute__((address_space(1))) void*)g,
        (__attribute__((address_space(3))) void*)l, 16, 0, 0);
}

// ---------------------------------------------------------------- gate ------
__global__ __launch_bounds__(64) void gate_kernel(
    const float* __restrict__ x, const float* __restrict__ gw,
    const float* __restrict__ gb,
    int* __restrict__ counts, int* __restrict__ etok, float* __restrict__ ew)
{
    const int t = blockIdx.x;
    const int lane = threadIdx.x;
    float s[NE];
#pragma unroll
    for (int e = 0; e < NE; ++e) s[e] = 0.f;
    const float* xr = x + (size_t)t * H_DIM;
    for (int i = lane; i < H_DIM; i += 64) {
        float xv = xr[i];
#pragma unroll
        for (int e = 0; e < NE; ++e) s[e] += xv * gw[e * H_DIM + i];
    }
#pragma unroll
    for (int e = 0; e < NE; ++e) {
        for (int off = 32; off > 0; off >>= 1) s[e] += __shfl_xor(s[e], off);
    }
    if (lane == 0) {
        float scores[NE], sfc[NE];
#pragma unroll
        for (int e = 0; e < NE; ++e) {
            scores[e] = 1.f / (1.f + __expf(-s[e]));
            sfc[e] = scores[e] + gb[e];
        }
        float gsc[4];
#pragma unroll
        for (int g = 0; g < 4; ++g) {
            float m1 = -1e30f, m2 = -1e30f;
#pragma unroll
            for (int j = 0; j < 4; ++j) {
                float v = sfc[4 * g + j];
                if (v > m1) { m2 = m1; m1 = v; } else if (v > m2) { m2 = v; }
            }
            gsc[g] = m1 + m2;
        }
        int g1 = 0;
        for (int g = 1; g < 4; ++g) if (gsc[g] > gsc[g1]) g1 = g;
        int g2 = -1;
        for (int g = 0; g < 4; ++g) {
            if (g == g1) continue;
            if (g2 < 0 || gsc[g] > gsc[g2]) g2 = g;
        }
        float tmp[NE];
#pragma unroll
        for (int e = 0; e < NE; ++e) {
            int gg = e >> 2;
            tmp[e] = (gg == g1 || gg == g2) ? sfc[e] : 0.0f;
        }
        int idxs[4]; float wk[4]; float wsum = 0.f;
#pragma unroll
        for (int k = 0; k < 4; ++k) {
            int bi = 0;
            for (int e = 1; e < NE; ++e) if (tmp[e] > tmp[bi]) bi = e;
            idxs[k] = bi; wk[k] = scores[bi]; wsum += scores[bi];
            tmp[bi] = -1e30f;
        }
        float inv = 1.f / (wsum + 1e-20f);
        for (int k = 0; k < 4; ++k) {
            int e = idxs[k];
            int pos = atomicAdd(&counts[e], 1);
            etok[e * T_TOK + pos] = t;
            ew[e * T_TOK + pos] = wk[k] * inv;   // SCALE = 1.0
        }
    }
}

// ---------------------------------------------------- x f32 -> bf16 ---------
__global__ __launch_bounds__(256) void cvtx_kernel(
    const float* __restrict__ x, __hip_bfloat16* __restrict__ x_bf)
{
    int i = (blockIdx.x * 256 + threadIdx.x) * 4;
    float4 v = ((const float4*)x)[i >> 2];
    x_bf[i + 0] = __float2bfloat16(v.x);
    x_bf[i + 1] = __float2bfloat16(v.y);
    x_bf[i + 2] = __float2bfloat16(v.z);
    x_bf[i + 3] = __float2bfloat16(v.w);
}

// ------------------------------------------------------------- gate/up ------
// Grid (22, ne, 4). Block = [BM=256 tok x 64 I-cols]; wave w owns 64 tokens.
// RING-3 + COUNTED vmcnt (the T3/T4 discipline): per step, wait vmcnt(4)
// (drains DMA for buf k + A(k) prefetched last step; leaves DMA(k+1)'s 4 ops
// in flight ACROSS the barrier), barrier, prefetch A(k+1), issue DMA(k+2)
// into buf (k+2)%3, then ds_read+cvt+MFMA on buf k%3. DMA gets ~2 steps of
// latency cover instead of <1. Ring-3 race-free: buf(k+2)%3 = buf(k-1)%3,
// whose reads completed before barrier k.
__global__ __launch_bounds__(256, 2) void gateup_kernel(
    const __hip_bfloat16* __restrict__ x_bf,
    const float* __restrict__ gproj, const float* __restrict__ uproj,
    const float* __restrict__ sgw, const float* __restrict__ suw,
    const int* __restrict__ counts, const int* __restrict__ etok,
    __hip_bfloat16* __restrict__ act, int e0)
{
    const int slot = blockIdx.y;
    const int e = e0 + slot;
    const int cnt = (e < NE) ? counts[e] : T_TOK;
    const int row0 = blockIdx.z * BM;
    if (row0 >= cnt) return;

    __shared__ int toks[BM];
    __shared__ __align__(16) float Bg[3][2048];   // [buf][64 rows x 32 K f32]
    __shared__ __align__(16) float Bu[3][2048];

    const int tid = threadIdx.x;
    {
        int r = row0 + tid;
        toks[tid] = (e < NE) ? ((r < cnt) ? etok[e * T_TOK + r] : 0) : r;
    }

    const int nb0 = blockIdx.x * 64;
    const float *wg, *wu;
    if (e < NE) {
        wg = gproj + (size_t)e * I_DIM * H_DIM;
        wu = uproj + (size_t)e * I_DIM * H_DIM;
    } else {
        wg = sgw + (size_t)(e - NE) * I_DIM * H_DIM;
        wu = suw + (size_t)(e - NE) * I_DIM * H_DIM;
    }

    const int lane = tid & 63;
    const int w = tid >> 6;
    const int col = lane & 15, kq = lane >> 4;

    // producer: wave w stages chunks {2w,2w+1} (1KB each) per matrix.
    // chunk c: lane l -> LDS f32 idx c*256 + l*4, i.e. row=c*8+(l>>3),
    // slot s=l&7. Source slot pre-swizzled: s ^ (row&7).
    const int lr8 = lane >> 3;
    const int sgx = (lane & 7) ^ lr8;
    const float* pgW[2]; const float* puW[2];
#pragma unroll
    for (int j = 0; j < 2; ++j) {
        int c = 2 * w + j;
        pgW[j] = wg + (size_t)(nb0 + c * 8 + lr8) * H_DIM + sgx * 4;
        puW[j] = wu + (size_t)(nb0 + c * 8 + lr8) * H_DIM + sgx * 4;
    }
    const int ldsw0 = (2 * w) * 256, ldsw1 = (2 * w + 1) * 256;

    // consumer: fragment ni, half h: row=ni*16+col,
    // f32 idx = row*32 + ((kq*2+h)^(row&7))*4
    int offs[4][2];
#pragma unroll
    for (int ni = 0; ni < 4; ++ni) {
        int row = ni * 16 + col;
#pragma unroll
        for (int h = 0; h < 2; ++h)
            offs[ni][h] = row * 32 + (((kq * 2 + h) ^ (row & 7)) << 2);
    }

    __syncthreads();   // toks visible

    const __hip_bfloat16* ar[4];
#pragma unroll
    for (int mi = 0; mi < 4; ++mi)
        ar[mi] = x_bf + (size_t)toks[w * 64 + mi * 16 + col] * H_DIM + kq * 8;

    f32x4 accg[4][4], accu[4][4];
#pragma unroll
    for (int mi = 0; mi < 4; ++mi)
#pragma unroll
        for (int ni = 0; ni < 4; ++ni) {
            accg[mi][ni] = (f32x4){0.f, 0.f, 0.f, 0.f};
            accu[mi][ni] = (f32x4){0.f, 0.f, 0.f, 0.f};
        }

    // prologue: A(0), then DMA k=0 -> buf0, k=1 -> buf1 (queue: A0,D0,D1)
    bf16x8 a_cur[4], a_nxt[4];
#pragma unroll
    for (int mi = 0; mi < 4; ++mi) a_cur[mi] = *(const bf16x8*)ar[mi];
    gll16(pgW[0], &Bg[0][ldsw0]); gll16(pgW[1], &Bg[0][ldsw1]);
    gll16(puW[0], &Bu[0][ldsw0]); gll16(puW[1], &Bu[0][ldsw1]);
    gll16(pgW[0] + 32, &Bg[1][ldsw0]); gll16(pgW[1] + 32, &Bg[1][ldsw1]);
    gll16(puW[0] + 32, &Bu[1][ldsw0]); gll16(puW[1] + 32, &Bu[1][ldsw1]);

    int br = 0;   // ring buffer holding step k
    for (int k = 0; k < 32; ++k) {
        // wait: drains DMA(buf k)+A(k), leaves DMA(k+1) (4 ops) in flight
        asm volatile("s_waitcnt vmcnt(4)" ::: "memory");
        __builtin_amdgcn_s_barrier();
        __builtin_amdgcn_sched_barrier(0);
        if (k + 1 < 32) {   // prefetch A(k+1)
#pragma unroll
            for (int mi = 0; mi < 4; ++mi)
                a_nxt[mi] = *(const bf16x8*)(ar[mi] + (k + 1) * 32);
        }
        __builtin_amdgcn_sched_barrier(0);
        if (k + 2 < 32) {   // stage k+2 into buf (k+2)%3 (== (k-1)%3)
            int b2 = br + 2; if (b2 >= 3) b2 -= 3;
            float* bgD = &Bg[0][0] + b2 * 2048;
            float* buD = &Bu[0][0] + b2 * 2048;
            const int ko = (k + 2) * 32;
            gll16(pgW[0] + ko, bgD + ldsw0); gll16(pgW[1] + ko, bgD + ldsw1);
            gll16(puW[0] + ko, buD + ldsw0); gll16(puW[1] + ko, buD + ldsw1);
        }
        __builtin_amdgcn_sched_barrier(0);
        const float* bgR = &Bg[0][0] + br * 2048;
        const float* buR = &Bu[0][0] + br * 2048;
        bf16x8 bg[4], bu[4];
#pragma unroll
        for (int ni = 0; ni < 4; ++ni) {
            float4 lo = *(const float4*)(bgR + offs[ni][0]);
            float4 hi = *(const float4*)(bgR + offs[ni][1]);
            bg[ni] = cvt8(lo, hi);
            float4 lo2 = *(const float4*)(buR + offs[ni][0]);
            float4 hi2 = *(const float4*)(buR + offs[ni][1]);
            bu[ni] = cvt8(lo2, hi2);
        }
#pragma unroll
        for (int mi = 0; mi < 4; ++mi)
#pragma unroll
            for (int ni = 0; ni < 4; ++ni) {
                accg[mi][ni] = __builtin_amdgcn_mfma_f32_16x16x32_bf16(a_cur[mi], bg[ni], accg[mi][ni], 0, 0, 0);
                accu[mi][ni] = __builtin_amdgcn_mfma_f32_16x16x32_bf16(a_cur[mi], bu[ni], accu[mi][ni], 0, 0, 0);
            }
#pragma unroll
        for (int mi = 0; mi < 4; ++mi) a_cur[mi] = a_nxt[mi];
        br += 1; if (br >= 3) br = 0;
    }

    // epilogue: silu(g)*u -> act (zeros for padded rows so down reads zeros)
#pragma unroll
    for (int mi = 0; mi < 4; ++mi)
#pragma unroll
        for (int ni = 0; ni < 4; ++ni)
#pragma unroll
            for (int r = 0; r < 4; ++r) {
                int lrow = w * 64 + mi * 16 + kq * 4 + r;
                int grow = row0 + lrow;
                float g = accg[mi][ni][r];
                float a = (grow < cnt) ? (g / (1.f + __expf(-g)) * accu[mi][ni][r]) : 0.f;
                act[((size_t)slot * T_TOK + grow) * I_DIM + nb0 + ni * 16 + col] =
                    __float2bfloat16(a);
            }
}

// ---------------------------------------------------------------- down ------
// 1-D grid, XCD-clustered (hw%8 picks the group). Same ring-3 counted-vmcnt
// K-loop; DMA batch = 2 ops -> wait vmcnt(2). K = I_DIM/32 = 44 steps.
__global__ __launch_bounds__(256, 3) void down_kernel(
    const __hip_bfloat16* __restrict__ act,
    const float* __restrict__ dproj, const float* __restrict__ sdw,
    const int* __restrict__ counts, const int* __restrict__ etok,
    const float* __restrict__ ew, float* __restrict__ y, int e0, int ne)
{
    const int hw = blockIdx.x;
    const int c8 = hw & 7, t = hw >> 3;
    const int nbt = t & 15, gh = t >> 4;
    const int g = c8 + 8 * gh;
    if (g >= ne * 4) return;           // Gp padding
    const int slot = g % ne;
    const int z = g / ne;

    const int e = e0 + slot;
    const int cnt = (e < NE) ? counts[e] : T_TOK;
    const int row0 = z * BM;
    if (row0 >= cnt) return;

    __shared__ int toks[BM];
    __shared__ float wts[BM];
    __shared__ __align__(16) float Bd[3][2048];

    const int tid = threadIdx.x;
    {
        int r = row0 + tid;
        if (e < NE) {
            bool ok = r < cnt;
            toks[tid] = ok ? etok[e * T_TOK + r] : 0;
            wts[tid]  = ok ? ew[e * T_TOK + r] : 0.f;
        } else { toks[tid] = r; wts[tid] = 1.f; }
    }

    const int nb0 = nbt * 64;
    const float* wd;
    int wstride;
    if (e < NE) { wd = dproj + (size_t)e * H_DIM * I_DIM; wstride = I_DIM; }
    else        { wd = sdw + (size_t)(e - NE) * I_DIM;    wstride = 2 * I_DIM; }

    const int lane = tid & 63;
    const int w = tid >> 6;
    const int col = lane & 15, kq = lane >> 4;

    const int lr8 = lane >> 3;
    const int sgx = (lane & 7) ^ lr8;
    const float* pdW[2];
#pragma unroll
    for (int j = 0; j < 2; ++j) {
        int c = 2 * w + j;
        pdW[j] = wd + (size_t)(nb0 + c * 8 + lr8) * wstride + sgx * 4;
    }
    const int ldsw0 = (2 * w) * 256, ldsw1 = (2 * w + 1) * 256;

    int offs[4][2];
#pragma unroll
    for (int ni = 0; ni < 4; ++ni) {
        int row = ni * 16 + col;
#pragma unroll
        for (int h = 0; h < 2; ++h)
            offs[ni][h] = row * 32 + (((kq * 2 + h) ^ (row & 7)) << 2);
    }

    __syncthreads();   // toks/wts visible

    const __hip_bfloat16* ar[4];
#pragma unroll
    for (int mi = 0; mi < 4; ++mi)
        ar[mi] = act + ((size_t)slot * T_TOK + row0 + w * 64 + mi * 16 + col) * I_DIM + kq * 8;

    f32x4 acc[4][4];
#pragma unroll
    for (int mi = 0; mi < 4; ++mi)
#pragma unroll
        for (int ni = 0; ni < 4; ++ni) acc[mi][ni] = (f32x4){0.f, 0.f, 0.f, 0.f};

    const int KS = I_DIM / 32;   // 44
    bf16x8 a_cur[4], a_nxt[4];
#pragma unroll
    for (int mi = 0; mi < 4; ++mi) a_cur[mi] = *(const bf16x8*)ar[mi];
    gll16(pdW[0], &Bd[0][ldsw0]); gll16(pdW[1], &Bd[0][ldsw1]);
    gll16(pdW[0] + 32, &Bd[1][ldsw0]); gll16(pdW[1] + 32, &Bd[1][ldsw1]);

    int br = 0;
    for (int k = 0; k < KS; ++k) {
        asm volatile("s_waitcnt vmcnt(2)" ::: "memory");
        __builtin_amdgcn_s_barrier();
        __builtin_amdgcn_sched_barrier(0);
        if (k + 1 < KS) {
#pragma unroll
            for (int mi = 0; mi < 4; ++mi)
                a_nxt[mi] = *(const bf16x8*)(ar[mi] + (k + 1) * 32);
        }
        __builtin_amdgcn_sched_barrier(0);
        if (k + 2 < KS) {
            int b2 = br + 2; if (b2 >= 3) b2 -= 3;
            float* bdD = &Bd[0][0] + b2 * 2048;
            const int ko = (k + 2) * 32;
            gll16(pdW[0] + ko, bdD + ldsw0); gll16(pdW[1] + ko, bdD + ldsw1);
        }
        __builtin_amdgcn_sched_barrier(0);
        const float* bdR = &Bd[0][0] + br * 2048;
        bf16x8 b[4];
#pragma unroll
        for (int ni = 0; ni < 4; ++ni) {
            float4 lo = *(const float4*)(bdR + offs[ni][0]);
            float4 hi = *(const float4*)(bdR + offs[ni][1]);
            b[ni] = cvt8(lo, hi);
        }
#pragma unroll
        for (int mi = 0; mi < 4; ++mi)
#pragma unroll
            for (int ni = 0; ni < 4; ++ni)
                acc[mi][ni] = __builtin_amdgcn_mfma_f32_16x16x32_bf16(a_cur[mi], b[ni], acc[mi][ni], 0, 0, 0);
#pragma unroll
        for (int mi = 0; mi < 4; ++mi) a_cur[mi] = a_nxt[mi];
        br += 1; if (br >= 3) br = 0;
    }

#pragma unroll
    for (int mi = 0; mi < 4; ++mi)
#pragma unroll
        for (int ni = 0; ni < 4; ++ni)
#pragma unroll
            for (int r = 0; r < 4; ++r) {
                int lrow = w * 64 + mi * 16 + kq * 4 + r;
                int grow = row0 + lrow;
                if (grow < cnt)
                    atomicAdd(&y[(size_t)toks[lrow] * H_DIM + nb0 + ni * 16 + col],
                              acc[mi][ni][r] * wts[lrow]);
            }
}

// -------------------------------------------------------------- launch ------
extern "C" void kernel_launch(void* const* d_in, const int* in_sizes, int n_in,
                              void* d_out, int out_size, void* d_ws, size_t ws_size,
                              hipStream_t stream) {
    (void)in_sizes; (void)n_in; (void)out_size;
    const float* x  = (const float*)d_in[0];
    const float* gw = (const float*)d_in[1];
    const float* gb = (const float*)d_in[2];
    const float* gp = (const float*)d_in[3];
    const float* up = (const float*)d_in[4];
    const float* dp = (const float*)d_in[5];
    const float* sg = (const float*)d_in[6];
    const float* su = (const float*)d_in[7];
    const float* sd = (const float*)d_in[8];
    float* out = (float*)d_out;

    char* ws = (char*)d_ws;
    int*   counts = (int*)ws;                                    // @0      (64 B)
    int*   etok   = (int*)(ws + 256);                            // 64 KB
    float* ew     = (float*)(ws + 256 + 65536);                  // 64 KB
    __hip_bfloat16* x_bf = (__hip_bfloat16*)(ws + 131328);       // 2 MB
    __hip_bfloat16* act  = (__hip_bfloat16*)(ws + 2228480);      // up to ~52 MB

    size_t fixed = 2228480;
    size_t per_e = (size_t)T_TOK * I_DIM * 2;                    // 2.75 MB / slot
    int cap = NEP;
    if (ws_size < fixed + (size_t)NEP * per_e) {
        cap = (ws_size > fixed + per_e) ? (int)((ws_size - fixed) / per_e) : 1;
        if (cap < 1) cap = 1;
    }

    hipMemsetAsync(ws, 0, 256, stream);                          // counts
    hipMemsetAsync(out, 0, (size_t)T_TOK * H_DIM * 4, stream);   // d_out is poisoned

    gate_kernel<<<dim3(T_TOK), dim3(64), 0, stream>>>(x, gw, gb, counts, etok, ew);
    cvtx_kernel<<<dim3(1024), dim3(256), 0, stream>>>(x, x_bf);

    for (int e0 = 0; e0 < NEP; e0 += cap) {
        int ne = NEP - e0 < cap ? NEP - e0 : cap;
        gateup_kernel<<<dim3(I_DIM / 64, ne, T_TOK / BM), dim3(256), 0, stream>>>(
            x_bf, gp, up, sg, su, counts, etok, act, e0);
        int Gp = ((ne * 4 + 7) / 8) * 8;                         // XCD-bijective pad
        down_kernel<<<dim3(16 * Gp), dim3(256), 0, stream>>>(
            act, dp, sd, counts, etok, ew, out, e0, ne);
    }
}